// Round 21
// baseline (116.337 us; speedup 1.0000x reference)
//
#include <hip/hip_runtime.h>

#define NSEQ 2048
#define SCALE 0.04419417382415922f
#define LOG2E 1.44269504088896f

typedef __attribute__((ext_vector_type(8))) short short8v;
typedef __attribute__((ext_vector_type(4))) float f32x4;

#define GLOAD_LDS16(g, l) __builtin_amdgcn_global_load_lds( \
    (const __attribute__((address_space(1))) void*)(g),     \
    (__attribute__((address_space(3))) void*)(l), 16, 0, 0)

__device__ __forceinline__ unsigned short f2bf(float f) {
    unsigned int u = __builtin_bit_cast(unsigned int, f);
    u += 0x7fff + ((u >> 16) & 1);
    return (unsigned short)(u >> 16);
}

__device__ __forceinline__ float exp2_fast(float x) {
    float r; asm("v_exp_f32 %0, %1" : "=v"(r) : "v"(x)); return r;
}

// pack(bf16_round(a) lo, bf16_round(b) hi) : 2 adds + 1 v_perm_b32
__device__ __forceinline__ unsigned int pack_bf16_rh(float a, float b) {
    unsigned int ua = __builtin_bit_cast(unsigned int, a) + 0x8000u;
    unsigned int ub = __builtin_bit_cast(unsigned int, b) + 0x8000u;
    return __builtin_amdgcn_perm(ub, ua, 0x07060302u);
}

// ---------------- fp32 -> bf16 convert, all three tensors in one launch ------
__global__ __launch_bounds__(256) void cvt_all(
    const float* __restrict__ x, const float* __restrict__ wq,
    const float* __restrict__ wo,
    unsigned short* __restrict__ xb, unsigned short* __restrict__ wqb,
    unsigned short* __restrict__ wob)
{
    int bid = blockIdx.x;
    const float* in;
    unsigned short* out;
    int i;
    if (bid < 4096)      { in = x;  out = xb;  i = bid * 256 + threadIdx.x; }
    else if (bid < 4864) { in = wq; out = wqb; i = (bid - 4096) * 256 + threadIdx.x; }
    else                 { in = wo; out = wob; i = (bid - 4864) * 256 + threadIdx.x; }
    float4 v = ((const float4*)in)[i];
    ushort4 o;
    o.x = f2bf(v.x); o.y = f2bf(v.y); o.z = f2bf(v.z); o.w = f2bf(v.w);
    ((ushort4*)out)[i] = o;
}

// ---------------- bf16 GEMM, BK=64, global_load_lds staging (R20, kept) ------
template<int MODE, int BM, int BN, int NX, int NWG>
__global__ __launch_bounds__(256) void gemm_bf16(
    const unsigned short* __restrict__ A,
    const unsigned short* __restrict__ W,
    const float* __restrict__ bias,
    unsigned short* __restrict__ Qws,
    unsigned short* __restrict__ Kws,
    unsigned short* __restrict__ Vtws,
    float* __restrict__ Cout)
{
    const int WM = BM / 2, WN = BN / 2;
    __shared__ __attribute__((aligned(16))) unsigned short As[BM * 64];
    __shared__ __attribute__((aligned(16))) unsigned short Bs[BN * 64];

    int tid = threadIdx.x;
    int lane = tid & 63, w = tid >> 6;
    int wm = w >> 1, wn = w & 1;
    int g = lane >> 4, fr = lane & 15;

    int id = blockIdx.x + NX * blockIdx.y;
    int wgid = (id & 7) * (NWG / 8) + (id >> 3);
    int m0 = (wgid / NX) * BM, n0 = (wgid % NX) * BN;

    f32x4 acc[WM / 16][4] = {};

    for (int k0 = 0; k0 < 512; k0 += 64) {
        __syncthreads();
#pragma unroll
        for (int c = 0; c < BM * 8 / 256; ++c) {
            int chunk = tid + c * 256;
            int row = chunk >> 3, c8 = chunk & 7;
            int gcol = (c8 ^ (row & 7)) * 8;
            GLOAD_LDS16(A + (size_t)(m0 + row) * 512 + k0 + gcol, &As[chunk * 8]);
        }
#pragma unroll
        for (int c = 0; c < BN * 8 / 256; ++c) {
            int chunk = tid + c * 256;
            int row = chunk >> 3, c8 = chunk & 7;
            int gcol = (c8 ^ (row & 7)) * 8;
            GLOAD_LDS16(W + (size_t)(n0 + row) * 512 + k0 + gcol, &Bs[chunk * 8]);
        }
        __syncthreads();
#pragma unroll
        for (int kk = 0; kk < 2; ++kk) {
            short8v af[WM / 16], bf[4];
#pragma unroll
            for (int mi = 0; mi < WM / 16; ++mi) {
                int row = wm * WM + mi * 16 + fr;
                af[mi] = *(const short8v*)(&As[row * 64 + (((kk * 4 + g) ^ (row & 7)) * 8)]);
            }
#pragma unroll
            for (int ni = 0; ni < 4; ++ni) {
                int row = wn * WN + ni * 16 + fr;
                bf[ni] = *(const short8v*)(&Bs[row * 64 + (((kk * 4 + g) ^ (row & 7)) * 8)]);
            }
#pragma unroll
            for (int mi = 0; mi < WM / 16; ++mi)
#pragma unroll
                for (int ni = 0; ni < 4; ++ni)
                    acc[mi][ni] = __builtin_amdgcn_mfma_f32_16x16x32_bf16(
                        af[mi], bf[ni], acc[mi][ni], 0, 0, 0);
        }
    }

#pragma unroll
    for (int mi = 0; mi < WM / 16; ++mi) {
#pragma unroll
        for (int ni = 0; ni < 4; ++ni) {
            int col = n0 + wn * WN + ni * 16 + fr;
            float bb = bias[col];
            int row0 = m0 + wm * WM + mi * 16 + g * 4;
            if (MODE == 0) {
                int b = row0 >> 11, s0 = row0 & 2047;
                if (col < 512) {
                    int h = col >> 6, d = col & 63;
#pragma unroll
                    for (int r = 0; r < 4; ++r)
                        Qws[(((size_t)(b * 8 + h) * NSEQ + s0 + r) << 6) + d] =
                            f2bf((acc[mi][ni][r] + bb) * (SCALE * LOG2E));
                } else if (col < 1024) {
                    int c2 = col - 512; int h = c2 >> 6, d = c2 & 63;
#pragma unroll
                    for (int r = 0; r < 4; ++r)
                        Kws[(((size_t)(b * 8 + h) * NSEQ + s0 + r) << 6) + d] =
                            f2bf(acc[mi][ni][r] + bb);
                } else {
                    int c2 = col - 1024; int h = c2 >> 6, d = c2 & 63;
                    uint2 pv;
                    pv.x = pack_bf16_rh(acc[mi][ni][0] + bb, acc[mi][ni][1] + bb);
                    pv.y = pack_bf16_rh(acc[mi][ni][2] + bb, acc[mi][ni][3] + bb);
                    *(uint2*)(&Vtws[((size_t)(b * 8 + h) * 64 + d) * NSEQ + s0]) = pv;
                }
            } else {
#pragma unroll
                for (int r = 0; r < 4; ++r)
                    Cout[(size_t)(row0 + r) * 512 + col] = acc[mi][ni][r] + bb;
            }
        }
    }
}

// ---------------- fused attention: 32q/wave + within-block kt-split ----------
// Block = 512 thr = 8 waves = 2 groups x 4 waves, one (b,h), 128 q-rows.
// Group G covers keys [G*1024, G*1024+1024): 16 tiles, single-buffered K/V.
// Each wave: 32 q-rows (2 16-row halves), K/V frag reads SHARED across halves
// -> LDS-ops per unit work 0.62x of R12. Fixed-max softmax => group partials
// exactly additive; in-LDS combine at end (no global partials).
// LDS: K 2x8KB + V 2x8KB + P 8x4KB = 64KB -> 2 blocks/CU at grid 512 (16 w/CU).
// K swizzle keyed (row>>2)&7 (stride-4 frag reads), V keyed row&7 (R12-best).
__global__ __launch_bounds__(512, 2) void attn_kernel(
    const unsigned short* __restrict__ Qws,
    const unsigned short* __restrict__ Kws,
    const unsigned short* __restrict__ Vtws,
    const float* __restrict__ A_phi,
    const float* __restrict__ gamma_p,
    unsigned short* __restrict__ Oout)
{
    __shared__ __attribute__((aligned(16))) unsigned short lds[32768];  // 64KB
    // ushort offsets: Ks(G): G*4096 [0,8192) ; Vts(G): 8192+G*4096 [8192,16384)
    //                 Pl(w): 16384 + w*2048  [16384,32768)

    int tid = threadIdx.x, lane = tid & 63, w = tid >> 6;
    int g = lane >> 4, fr = lane & 15;
    int G = w >> 2, wg = w & 3;

    // XCD swizzle: id%8 pins batch b to an XCD pair (A_phi L2 reuse)
    int id = blockIdx.x;                 // 0..511
    int b = (id & 7) >> 1, p = id & 1;
    int j = id >> 3;                     // 0..63
    int h = j & 7;
    int qt = ((j >> 3) << 1) | p;        // 0..15
    int bh = b * 8 + h;
    int q0 = qt * 128 + wg * 32;         // wave's 32-row q base
    float g2 = gamma_p[0] * LOG2E;

    const unsigned short* Kb = Kws + (size_t)bh * NSEQ * 64;
    const unsigned short* Vb = Vtws + (size_t)bh * 64 * NSEQ;
    const float* Ap = A_phi + (size_t)b * NSEQ * NSEQ;

    // Q fragments, both halves
    short8v qf[2][2];
#pragma unroll
    for (int qs = 0; qs < 2; ++qs)
#pragma unroll
        for (int dc = 0; dc < 2; ++dc)
            qf[qs][dc] = *(const short8v*)(
                Qws + ((size_t)bh * NSEQ + q0 + qs * 16 + fr) * 64 + dc * 32 + g * 8);

    // staging: 256 threads/group stage the group's 8KB K + 8KB V tile.
    // thread cg handles 16B chunks cg and cg+256 of each.
    int cg = tid & 255;
    int sr0 = cg >> 3, sc0 = cg & 7;             // chunk cg
    int sr1 = (cg + 256) >> 3, sc1 = cg & 7;     // chunk cg+256
    int swK0 = (sc0 ^ ((sr0 >> 2) & 7)) * 8, swK1 = (sc1 ^ ((sr1 >> 2) & 7)) * 8;
    int swV0 = (sc0 ^ (sr0 & 7)) * 8,        swV1 = (sc1 ^ (sr1 & 7)) * 8;
    unsigned short* KsG = &lds[G * 4096];
    unsigned short* VsG = &lds[8192 + G * 4096];
    unsigned short* Pw  = &lds[16384 + w * 2048];
    int tile0 = G * 16;

    float l_lane[2][4] = {};
    f32x4 o_acc[2][4] = {};

    // prologue: stage the group's first tile
    {
        short8v k0 = *(const short8v*)(Kb + tile0 * 4096 + cg * 8);
        short8v k1 = *(const short8v*)(Kb + tile0 * 4096 + (cg + 256) * 8);
        short8v v0 = *(const short8v*)(Vb + (size_t)sr0 * NSEQ + tile0 * 64 + sc0 * 8);
        short8v v1 = *(const short8v*)(Vb + (size_t)sr1 * NSEQ + tile0 * 64 + sc1 * 8);
        *(short8v*)(&KsG[sr0 * 64 + swK0]) = k0;
        *(short8v*)(&KsG[sr1 * 64 + swK1]) = k1;
        *(short8v*)(&VsG[sr0 * 64 + swV0]) = v0;
        *(short8v*)(&VsG[sr1 * 64 + swV1]) = v1;
    }
    __syncthreads();

    for (int t = 0; t < 16; ++t) {
        int tile = tile0 + t;

        // T14: issue next-tile global loads early (held in regs)
        short8v k0r, k1r, v0r, v1r;
        if (t < 15) {
            k0r = *(const short8v*)(Kb + (tile + 1) * 4096 + cg * 8);
            k1r = *(const short8v*)(Kb + (tile + 1) * 4096 + (cg + 256) * 8);
            v0r = *(const short8v*)(Vb + (size_t)sr0 * NSEQ + (tile + 1) * 64 + sc0 * 8);
            v1r = *(const short8v*)(Vb + (size_t)sr1 * NSEQ + (tile + 1) * 64 + sc1 * 8);
        }

        // A_phi half 0 (hides under QK)
        float4 av0[4];
#pragma unroll
        for (int r = 0; r < 4; ++r)
            av0[r] = *(const float4*)(Ap + (size_t)(q0 + g * 4 + r) * NSEQ + tile * 64 + 4 * fr);

        // QK both halves: 8 K-frag reads shared (the 32q payoff)
        f32x4 sa[2][4] = {};
        __builtin_amdgcn_s_setprio(1);
#pragma unroll
        for (int kf = 0; kf < 4; ++kf) {
            int row = 4 * fr + kf;
#pragma unroll
            for (int dc = 0; dc < 2; ++dc) {
                short8v kfrag = *(const short8v*)(
                    &KsG[row * 64 + (((dc * 4 + g) ^ ((row >> 2) & 7)) * 8)]);
                sa[0][kf] = __builtin_amdgcn_mfma_f32_16x16x32_bf16(qf[0][dc], kfrag, sa[0][kf], 0, 0, 0);
                sa[1][kf] = __builtin_amdgcn_mfma_f32_16x16x32_bf16(qf[1][dc], kfrag, sa[1][kf], 0, 0, 0);
            }
        }
        __builtin_amdgcn_s_setprio(0);

        // A_phi half 1 (hides under half-0 exp)
        float4 av1[4];
#pragma unroll
        for (int r = 0; r < 4; ++r)
            av1[r] = *(const float4*)(Ap + (size_t)(q0 + 16 + g * 4 + r) * NSEQ + tile * 64 + 4 * fr);

        // exp + P-relay, both halves (separate Pl rows -> no hazard)
#pragma unroll
        for (int qs = 0; qs < 2; ++qs) {
#pragma unroll
            for (int r = 0; r < 4; ++r) {
                float4 a = (qs == 0) ? av0[r] : av1[r];
                float e0 = exp2_fast(fmaf(g2, a.x, sa[qs][0][r]));
                float e1 = exp2_fast(fmaf(g2, a.y, sa[qs][1][r]));
                float e2 = exp2_fast(fmaf(g2, a.z, sa[qs][2][r]));
                float e3 = exp2_fast(fmaf(g2, a.w, sa[qs][3][r]));
                l_lane[qs][r] += (e0 + e1) + (e2 + e3);
                int rp = qs * 16 + g * 4 + r;
                uint2 pp;
                pp.x = pack_bf16_rh(e0, e1);
                pp.y = pack_bf16_rh(e2, e3);
                *(uint2*)(&Pw[rp * 64 + (((fr >> 1) ^ (rp & 7)) * 8) + (fr & 1) * 4]) = pp;
            }
        }
        asm volatile("s_waitcnt lgkmcnt(0)" ::: "memory");

        // PV both halves, V-frags read once
#pragma unroll
        for (int kc = 0; kc < 2; ++kc) {
            short8v pf0 = *(const short8v*)(&Pw[fr * 64 + (((kc * 4 + g) ^ (fr & 7)) * 8)]);
            short8v pf1 = *(const short8v*)(&Pw[(16 + fr) * 64 + (((kc * 4 + g) ^ (fr & 7)) * 8)]);
            __builtin_amdgcn_s_setprio(1);
#pragma unroll
            for (int nf = 0; nf < 4; ++nf) {
                int vrow = nf * 16 + fr;
                short8v vf = *(const short8v*)(
                    &VsG[vrow * 64 + (((kc * 4 + g) ^ (vrow & 7)) * 8)]);
                o_acc[0][nf] = __builtin_amdgcn_mfma_f32_16x16x32_bf16(pf0, vf, o_acc[0][nf], 0, 0, 0);
                o_acc[1][nf] = __builtin_amdgcn_mfma_f32_16x16x32_bf16(pf1, vf, o_acc[1][nf], 0, 0, 0);
            }
            __builtin_amdgcn_s_setprio(0);
        }

        // single-buffer swap: all reads done -> write staged regs -> visible
        __syncthreads();
        if (t < 15) {
            *(short8v*)(&KsG[sr0 * 64 + swK0]) = k0r;
            *(short8v*)(&KsG[sr1 * 64 + swK1]) = k1r;
            *(short8v*)(&VsG[sr0 * 64 + swV0]) = v0r;
            *(short8v*)(&VsG[sr1 * 64 + swV1]) = v1r;
        }
        __syncthreads();
    }

    // l-reduce per half (q-row = per (g?no) .. reduce over fr-bits)
    float lred[2][4];
#pragma unroll
    for (int qs = 0; qs < 2; ++qs)
#pragma unroll
        for (int r = 0; r < 4; ++r) {
            float l = l_lane[qs][r];
            l += __shfl_xor(l, 1);
            l += __shfl_xor(l, 2);
            l += __shfl_xor(l, 4);
            l += __shfl_xor(l, 8);
            lred[qs][r] = l;
        }

    // cross-group combine via LDS (reuse K/V regions = 32KB; Lb in Pl region)
    float* Ob = (float*)&lds[0];          // [4 waves][32 rows][64] fp32
    float* Lb = (float*)&lds[16384];      // [128 rows] fp32
    if (G == 1) {
#pragma unroll
        for (int qs = 0; qs < 2; ++qs)
#pragma unroll
            for (int r = 0; r < 4; ++r) {
                int row = qs * 16 + g * 4 + r;
#pragma unroll
                for (int nf = 0; nf < 4; ++nf)
                    Ob[(wg * 32 + row) * 64 + nf * 16 + fr] = o_acc[qs][nf][r];
                if (fr == 0) Lb[wg * 32 + row] = lred[qs][r];
            }
    }
    __syncthreads();
    if (G == 0) {
#pragma unroll
        for (int qs = 0; qs < 2; ++qs)
#pragma unroll
            for (int r = 0; r < 4; ++r) {
                int row = qs * 16 + g * 4 + r;
                float inv = 1.0f / (lred[qs][r] + Lb[wg * 32 + row]);
                int qg = q0 + row;
#pragma unroll
                for (int nf = 0; nf < 4; ++nf) {
                    float val = (o_acc[qs][nf][r] + Ob[(wg * 32 + row) * 64 + nf * 16 + fr]) * inv;
                    Oout[((size_t)b * NSEQ + qg) * 512 + h * 64 + nf * 16 + fr] = f2bf(val);
                }
            }
    }
}

extern "C" void kernel_launch(void* const* d_in, const int* in_sizes, int n_in,
                              void* d_out, int out_size, void* d_ws, size_t ws_size,
                              hipStream_t stream) {
    const float* x      = (const float*)d_in[0];
    const float* A_phi  = (const float*)d_in[1];
    const float* w_qkv  = (const float*)d_in[2];
    const float* b_qkv  = (const float*)d_in[3];
    const float* w_out  = (const float*)d_in[4];
    const float* b_out  = (const float*)d_in[5];
    const float* gamma  = (const float*)d_in[6];
    float* out = (float*)d_out;

    unsigned short* xb   = (unsigned short*)d_ws;
    unsigned short* wqb  = xb  + (size_t)8192 * 512;
    unsigned short* wob  = wqb + (size_t)1536 * 512;
    unsigned short* Qws  = wob + (size_t)512 * 512;
    unsigned short* Kws  = Qws + (size_t)4 * 8 * NSEQ * 64;
    unsigned short* Vtws = Kws + (size_t)4 * 8 * NSEQ * 64;
    unsigned short* Oat  = Vtws + (size_t)4 * 8 * NSEQ * 64;

    cvt_all<<<dim3(5120), dim3(256), 0, stream>>>(x, w_qkv, w_out, xb, wqb, wob);

    gemm_bf16<0, 128, 128, 12, 768><<<dim3(12, 64), dim3(256), 0, stream>>>(
        xb, wqb, b_qkv, Qws, Kws, Vtws, nullptr);

    attn_kernel<<<dim3(512), dim3(512), 0, stream>>>(
        Qws, Kws, Vtws, A_phi, gamma, Oat);

    gemm_bf16<1, 64, 128, 4, 512><<<dim3(4, 128), dim3(256), 0, stream>>>(
        Oat, wob, b_out, nullptr, nullptr, nullptr, out);
}

// Round 22
// 104.470 us; speedup vs baseline: 1.1136x; 1.1136x over previous
//
#include <hip/hip_runtime.h>

#define NSEQ 2048
#define SCALE 0.04419417382415922f
#define LOG2E 1.44269504088896f

typedef __attribute__((ext_vector_type(8))) short short8v;
typedef __attribute__((ext_vector_type(4))) float f32x4;

#define GLOAD_LDS16(g, l) __builtin_amdgcn_global_load_lds( \
    (const __attribute__((address_space(1))) void*)(g),     \
    (__attribute__((address_space(3))) void*)(l), 16, 0, 0)

__device__ __forceinline__ unsigned short f2bf(float f) {
    unsigned int u = __builtin_bit_cast(unsigned int, f);
    u += 0x7fff + ((u >> 16) & 1);
    return (unsigned short)(u >> 16);
}

__device__ __forceinline__ float exp2_fast(float x) {
    float r; asm("v_exp_f32 %0, %1" : "=v"(r) : "v"(x)); return r;
}

// pack(bf16_round(a) lo, bf16_round(b) hi) : 2 adds + 1 v_perm_b32
__device__ __forceinline__ unsigned int pack_bf16_rh(float a, float b) {
    unsigned int ua = __builtin_bit_cast(unsigned int, a) + 0x8000u;
    unsigned int ub = __builtin_bit_cast(unsigned int, b) + 0x8000u;
    return __builtin_amdgcn_perm(ub, ua, 0x07060302u);
}

// ---------------- fp32 -> bf16 convert, all three tensors in one launch ------
__global__ __launch_bounds__(256) void cvt_all(
    const float* __restrict__ x, const float* __restrict__ wq,
    const float* __restrict__ wo,
    unsigned short* __restrict__ xb, unsigned short* __restrict__ wqb,
    unsigned short* __restrict__ wob)
{
    int bid = blockIdx.x;
    const float* in;
    unsigned short* out;
    int i;
    if (bid < 4096)      { in = x;  out = xb;  i = bid * 256 + threadIdx.x; }
    else if (bid < 4864) { in = wq; out = wqb; i = (bid - 4096) * 256 + threadIdx.x; }
    else                 { in = wo; out = wob; i = (bid - 4864) * 256 + threadIdx.x; }
    float4 v = ((const float4*)in)[i];
    ushort4 o;
    o.x = f2bf(v.x); o.y = f2bf(v.y); o.z = f2bf(v.z); o.w = f2bf(v.w);
    ((ushort4*)out)[i] = o;
}

// ---------------- bf16 GEMM, BK=64, global_load_lds staging ------------------
// Tile BM x BN, 4 waves as 2x2. NX = grid width (compile-time for cheap div).
// XCD-aware swizzle: wgid=(id&7)*(nwg/8)+(id>>3) pins 8 consecutive m-rows
// per XCD -> A-panels + B stay L2-resident (T1; nwg%8==0 bijective).
// MODE 0 (128x128): scatter to Q (scaled), K, V^T; V-writes packed b64.
// MODE 1 (64x128):  fp32 out + bias.
template<int MODE, int BM, int BN, int NX, int NWG>
__global__ __launch_bounds__(256) void gemm_bf16(
    const unsigned short* __restrict__ A,
    const unsigned short* __restrict__ W,
    const float* __restrict__ bias,
    unsigned short* __restrict__ Qws,
    unsigned short* __restrict__ Kws,
    unsigned short* __restrict__ Vtws,
    float* __restrict__ Cout)
{
    const int WM = BM / 2, WN = BN / 2;
    __shared__ __attribute__((aligned(16))) unsigned short As[BM * 64];
    __shared__ __attribute__((aligned(16))) unsigned short Bs[BN * 64];

    int tid = threadIdx.x;
    int lane = tid & 63, w = tid >> 6;
    int wm = w >> 1, wn = w & 1;
    int g = lane >> 4, fr = lane & 15;

    int id = blockIdx.x + NX * blockIdx.y;
    int wgid = (id & 7) * (NWG / 8) + (id >> 3);
    int m0 = (wgid / NX) * BM, n0 = (wgid % NX) * BN;

    f32x4 acc[WM / 16][4] = {};

    for (int k0 = 0; k0 < 512; k0 += 64) {
        __syncthreads();
#pragma unroll
        for (int c = 0; c < BM * 8 / 256; ++c) {
            int chunk = tid + c * 256;
            int row = chunk >> 3, c8 = chunk & 7;
            int gcol = (c8 ^ (row & 7)) * 8;
            GLOAD_LDS16(A + (size_t)(m0 + row) * 512 + k0 + gcol, &As[chunk * 8]);
        }
#pragma unroll
        for (int c = 0; c < BN * 8 / 256; ++c) {
            int chunk = tid + c * 256;
            int row = chunk >> 3, c8 = chunk & 7;
            int gcol = (c8 ^ (row & 7)) * 8;
            GLOAD_LDS16(W + (size_t)(n0 + row) * 512 + k0 + gcol, &Bs[chunk * 8]);
        }
        __syncthreads();
#pragma unroll
        for (int kk = 0; kk < 2; ++kk) {
            short8v af[WM / 16], bf[4];
#pragma unroll
            for (int mi = 0; mi < WM / 16; ++mi) {
                int row = wm * WM + mi * 16 + fr;
                af[mi] = *(const short8v*)(&As[row * 64 + (((kk * 4 + g) ^ (row & 7)) * 8)]);
            }
#pragma unroll
            for (int ni = 0; ni < 4; ++ni) {
                int row = wn * WN + ni * 16 + fr;
                bf[ni] = *(const short8v*)(&Bs[row * 64 + (((kk * 4 + g) ^ (row & 7)) * 8)]);
            }
#pragma unroll
            for (int mi = 0; mi < WM / 16; ++mi)
#pragma unroll
                for (int ni = 0; ni < 4; ++ni)
                    acc[mi][ni] = __builtin_amdgcn_mfma_f32_16x16x32_bf16(
                        af[mi], bf[ni], acc[mi][ni], 0, 0, 0);
        }
    }

#pragma unroll
    for (int mi = 0; mi < WM / 16; ++mi) {
#pragma unroll
        for (int ni = 0; ni < 4; ++ni) {
            int col = n0 + wn * WN + ni * 16 + fr;
            float bb = bias[col];
            int row0 = m0 + wm * WM + mi * 16 + g * 4;
            if (MODE == 0) {
                int b = row0 >> 11, s0 = row0 & 2047;
                if (col < 512) {
                    int h = col >> 6, d = col & 63;
#pragma unroll
                    for (int r = 0; r < 4; ++r)
                        Qws[(((size_t)(b * 8 + h) * NSEQ + s0 + r) << 6) + d] =
                            f2bf((acc[mi][ni][r] + bb) * (SCALE * LOG2E));
                } else if (col < 1024) {
                    int c2 = col - 512; int h = c2 >> 6, d = c2 & 63;
#pragma unroll
                    for (int r = 0; r < 4; ++r)
                        Kws[(((size_t)(b * 8 + h) * NSEQ + s0 + r) << 6) + d] =
                            f2bf(acc[mi][ni][r] + bb);
                } else {
                    int c2 = col - 1024; int h = c2 >> 6, d = c2 & 63;
                    uint2 pv;
                    pv.x = pack_bf16_rh(acc[mi][ni][0] + bb, acc[mi][ni][1] + bb);
                    pv.y = pack_bf16_rh(acc[mi][ni][2] + bb, acc[mi][ni][3] + bb);
                    *(uint2*)(&Vtws[((size_t)(b * 8 + h) * 64 + d) * NSEQ + s0]) = pv;
                }
            } else {
#pragma unroll
                for (int r = 0; r < 4; ++r)
                    Cout[(size_t)(row0 + r) * 512 + col] = acc[mi][ni][r] + bb;
            }
        }
    }
}

// ---------------- fused attention (R12 measured-best: attn ~70us) -----------
// Block = 512 thr = 8 waves, one (b,h); wave w owns 16 q-rows.
// K/V tiles dbuf in XOR-swizzled LDS (48KB -> 3-blocks-capable, grid gives 2).
// K swizzle keyed (row>>2)&7 (stride-4-row frag reads), V keyed row&7
// (adjacent-row reads). T14 reg-staged dbuf. Fixed-max softmax:
// P = exp2(S + g2*A_phi), Q pre-scaled by SCALE*LOG2E.
__global__ __launch_bounds__(512, 3) void attn_kernel(
    const unsigned short* __restrict__ Qws,
    const unsigned short* __restrict__ Kws,
    const unsigned short* __restrict__ Vtws,
    const float* __restrict__ A_phi,
    const float* __restrict__ gamma_p,
    unsigned short* __restrict__ Oout)
{
    __shared__ __attribute__((aligned(16))) unsigned short Ks[2][64 * 64];
    __shared__ __attribute__((aligned(16))) unsigned short Vts[2][64 * 64];
    __shared__ __attribute__((aligned(16))) unsigned short Pl[8][16 * 64];

    int tid = threadIdx.x, lane = tid & 63, w = tid >> 6;
    int g = lane >> 4, fr = lane & 15;

    int id = blockIdx.x;                 // 0..511
    int b = (id & 7) >> 1, p = id & 1;
    int j = id >> 3;                     // 0..63
    int h = j & 7;
    int qt = ((j >> 3) << 1) | p;        // 0..15
    int bh = b * 8 + h;
    int q0 = qt * 128 + w * 16;          // wave's q base
    float g2 = gamma_p[0] * LOG2E;

    const unsigned short* Kb = Kws + (size_t)bh * NSEQ * 64;
    const unsigned short* Vb = Vtws + (size_t)bh * 64 * NSEQ;
    const float* Ap = A_phi + (size_t)b * NSEQ * NSEQ;

    short8v qf[2];
#pragma unroll
    for (int dc = 0; dc < 2; ++dc)
        qf[dc] = *(const short8v*)(Qws + ((size_t)bh * NSEQ + q0 + fr) * 64 + dc * 32 + g * 8);

    int c = tid;
    int krow = c >> 3;
    int kchunk = c & 7;
    int swK = (kchunk ^ ((krow >> 2) & 7)) * 8;
    int swV = (kchunk ^ (krow & 7)) * 8;
    int kcol = kchunk * 8;

    float l_lane[4] = {};
    f32x4 o_acc[4] = {};

    {
        short8v k0v = *(const short8v*)(Kb + c * 8);
        short8v v0v = *(const short8v*)(Vb + (size_t)krow * NSEQ + kcol);
        *(short8v*)(&Ks[0][krow * 64 + swK]) = k0v;
        *(short8v*)(&Vts[0][krow * 64 + swV]) = v0v;
    }
    __syncthreads();

    for (int kt = 0; kt < NSEQ / 64; ++kt) {
        int cur = kt & 1;

        short8v kreg, vreg;
        if (kt < NSEQ / 64 - 1) {
            kreg = *(const short8v*)(Kb + (kt + 1) * 4096 + c * 8);
            vreg = *(const short8v*)(Vb + (size_t)krow * NSEQ + (kt + 1) * 64 + kcol);
        }

        float4 av[4];
#pragma unroll
        for (int r = 0; r < 4; ++r)
            av[r] = *(const float4*)(Ap + (size_t)(q0 + g * 4 + r) * NSEQ + kt * 64 + 4 * fr);

        f32x4 sa[4] = {};
        __builtin_amdgcn_s_setprio(1);
#pragma unroll
        for (int kf = 0; kf < 4; ++kf) {
            int row = 4 * fr + kf;
#pragma unroll
            for (int dc = 0; dc < 2; ++dc) {
                short8v kfrag = *(const short8v*)(
                    &Ks[cur][row * 64 + (((dc * 4 + g) ^ ((row >> 2) & 7)) * 8)]);
                sa[kf] = __builtin_amdgcn_mfma_f32_16x16x32_bf16(qf[dc], kfrag, sa[kf], 0, 0, 0);
            }
        }
        __builtin_amdgcn_s_setprio(0);

#pragma unroll
        for (int r = 0; r < 4; ++r) {
            float e0 = exp2_fast(fmaf(g2, av[r].x, sa[0][r]));
            float e1 = exp2_fast(fmaf(g2, av[r].y, sa[1][r]));
            float e2 = exp2_fast(fmaf(g2, av[r].z, sa[2][r]));
            float e3 = exp2_fast(fmaf(g2, av[r].w, sa[3][r]));
            l_lane[r] += (e0 + e1) + (e2 + e3);
            int rp = g * 4 + r;
            uint2 pp;
            pp.x = pack_bf16_rh(e0, e1);
            pp.y = pack_bf16_rh(e2, e3);
            *(uint2*)(&Pl[w][rp * 64 + (((fr >> 1) ^ (rp & 7)) * 8) + (fr & 1) * 4]) = pp;
        }
        asm volatile("s_waitcnt lgkmcnt(0)" ::: "memory");

#pragma unroll
        for (int kc = 0; kc < 2; ++kc) {
            short8v pf = *(const short8v*)(
                &Pl[w][fr * 64 + (((kc * 4 + g) ^ (fr & 7)) * 8)]);
            __builtin_amdgcn_s_setprio(1);
#pragma unroll
            for (int nf = 0; nf < 4; ++nf) {
                int vrow = nf * 16 + fr;
                short8v vf = *(const short8v*)(
                    &Vts[cur][vrow * 64 + (((kc * 4 + g) ^ (vrow & 7)) * 8)]);
                o_acc[nf] = __builtin_amdgcn_mfma_f32_16x16x32_bf16(pf, vf, o_acc[nf], 0, 0, 0);
            }
            __builtin_amdgcn_s_setprio(0);
        }

        if (kt < NSEQ / 64 - 1) {
            *(short8v*)(&Ks[cur ^ 1][krow * 64 + swK]) = kreg;
            *(short8v*)(&Vts[cur ^ 1][krow * 64 + swV]) = vreg;
        }
        __syncthreads();
    }

#pragma unroll
    for (int r = 0; r < 4; ++r) {
        float l = l_lane[r];
        l += __shfl_xor(l, 1);
        l += __shfl_xor(l, 2);
        l += __shfl_xor(l, 4);
        l += __shfl_xor(l, 8);
        float inv = 1.0f / l;
        int qg = q0 + g * 4 + r;
#pragma unroll
        for (int nf = 0; nf < 4; ++nf)
            Oout[((size_t)b * NSEQ + qg) * 512 + h * 64 + nf * 16 + fr] =
                f2bf(o_acc[nf][r] * inv);
    }
}

extern "C" void kernel_launch(void* const* d_in, const int* in_sizes, int n_in,
                              void* d_out, int out_size, void* d_ws, size_t ws_size,
                              hipStream_t stream) {
    const float* x      = (const float*)d_in[0];
    const float* A_phi  = (const float*)d_in[1];
    const float* w_qkv  = (const float*)d_in[2];
    const float* b_qkv  = (const float*)d_in[3];
    const float* w_out  = (const float*)d_in[4];
    const float* b_out  = (const float*)d_in[5];
    const float* gamma  = (const float*)d_in[6];
    float* out = (float*)d_out;

    unsigned short* xb   = (unsigned short*)d_ws;
    unsigned short* wqb  = xb  + (size_t)8192 * 512;
    unsigned short* wob  = wqb + (size_t)1536 * 512;
    unsigned short* Qws  = wob + (size_t)512 * 512;
    unsigned short* Kws  = Qws + (size_t)4 * 8 * NSEQ * 64;
    unsigned short* Vtws = Kws + (size_t)4 * 8 * NSEQ * 64;
    unsigned short* Oat  = Vtws + (size_t)4 * 8 * NSEQ * 64;

    cvt_all<<<dim3(5120), dim3(256), 0, stream>>>(x, w_qkv, w_out, xb, wqb, wob);

    gemm_bf16<0, 128, 128, 12, 768><<<dim3(12, 64), dim3(256), 0, stream>>>(
        xb, wqb, b_qkv, Qws, Kws, Vtws, nullptr);

    attn_kernel<<<dim3(512), dim3(512), 0, stream>>>(
        Qws, Kws, Vtws, A_phi, gamma, Oat);

    gemm_bf16<1, 64, 128, 4, 512><<<dim3(4, 128), dim3(256), 0, stream>>>(
        Oat, wob, b_out, nullptr, nullptr, nullptr, out);
}